// Round 6
// baseline (122.110 us; speedup 1.0000x reference)
//
#include <hip/hip_runtime.h>
#include <hip/hip_bf16.h>

// Problem: x(4,256,64,64), offset(4,18,64,64), mask(4,9,64,64),
// weight(256,256,3,3) -> out(4,256,64,64). stride=1, pad=1, K=3.
// R16: r32c32 wave retile to halve A-tile LDS read amplification.
// R15 post-mortem (miss): B-L2 halved but LDS A-reads DOUBLED (af[4] x16
// waves = 16x amplification of the 4KB/ks slab -> 1.18GB chip-wide);
// SQ_LDS_BANK_CONFLICT doubled to 4.9M. LDS read pipe ~15-23us/CU is the
// bottleneck. Geometry: wave tile r x c (rc=1024): A-LDS = (256/c)*4KB/ks,
// B-VMEM = (64/r)*16KB/ks. r=c=32 balances: A-LDS 32KB + B-VMEM 32KB per
// block-ks (B's 2x amp absorbed by L1: sharing wave-pair is in-block).
// Wave wv: wg=wv>>3 (row half), cg=wv&7 (32-col group); acc[2][2], af[2],
// bfx[2][2] ring. Sampling/desc/T14/non-draining-barrier/setprio kept.
#define CN 256
#define HN 64
#define WN 64
#define ON 256
#define KKN 9
#define HWN 4096
#define KDIM 2304   // 9*256
#define KC 288      // KDIM/8 chunks

using frag_ab = __attribute__((ext_vector_type(8))) short;  // 8 bf16
using frag_cd = __attribute__((ext_vector_type(4))) float;  // 4 fp32
using short4v = __attribute__((ext_vector_type(4))) short;  // 4 bf16 (8B)
using int4v   = __attribute__((ext_vector_type(4))) int;
using float4v = __attribute__((ext_vector_type(4))) float;
using float2v = __attribute__((ext_vector_type(2))) float;
using uint2v  = __attribute__((ext_vector_type(2))) unsigned;

static __device__ inline short f2bf(float f) {
    union { float f; unsigned u; } v; v.f = f;
    unsigned r = v.u + 0x7fffu + ((v.u >> 16) & 1u);
    return (short)(r >> 16);
}

// ---------- kernel 1: prep = transpose x -> BHWC bf16 | repack weight ----
__global__ __launch_bounds__(256) void prep_kernel(const float* __restrict__ x,
                                                   const float* __restrict__ wsrc,
                                                   short* __restrict__ xb16,
                                                   short* __restrict__ wtb) {
    int bidx = blockIdx.x;
    int tid  = threadIdx.x;
    if (bidx < 1024) {
        __shared__ float tile[64][65];
        int b   = bidx >> 8;
        int rem = bidx & 255;
        int c0  = (rem >> 6) * 64;
        int p0  = (rem & 63) * 64;
        int tp = tid & 63, tc = tid >> 6;
        for (int i = 0; i < 16; ++i) {
            int c = tc + i * 4;
            tile[c][tp] = x[(b * CN + c0 + c) * HWN + p0 + tp];
        }
        __syncthreads();
        int tcc = tid & 63, tpp = tid >> 6;
        for (int i = 0; i < 16; ++i) {
            int p = tpp + i * 4;
            xb16[(b * HWN + p0 + p) * CN + c0 + tcc] = f2bf(tile[tcc][p]);
        }
    } else {
        int chunk = (bidx - 1024) * 256 + tid;   // < 4*288*64 = 73728
        int ob  = chunk / (KC * 64);
        int rem = chunk - ob * (KC * 64);
        int kc  = rem >> 6;
        int row = rem & 63;
        int o   = ob * 64 + row;
        int kk  = kc >> 5;
        int oct = kc & 31;
        frag_ab v;
        #pragma unroll
        for (int e = 0; e < 8; ++e)
            v[e] = f2bf(wsrc[(o * CN + oct * 8 + e) * 9 + kk]);
        *(frag_ab*)&wtb[(size_t)chunk * 8] = v;
    }
}

// ---------- kernel 2: fused sample + GEMM ----------
// block: 64 m-rows (one (b,h) row) x 256 o-cols, 16 waves.
// wave wv: rows (wv>>3)*32..+32, cols (wv&7)*32..+32 (acc 2x2);
// sampling rows wv*4..+4. Per kk: issue B(ks0/ks1) -> combine ->
// prefetch_x(kk+1) -> lgkmcnt(0)+s_barrier (no vmcnt drain) ->
// 8 ks x {2 ds_read A, 4 MFMA, reload B ks+2}.
__global__ __launch_bounds__(1024, 4) void fused_kernel(const short* __restrict__ xb16,
                                                        const short* __restrict__ wtb,
                                                        const float* __restrict__ offs,
                                                        const float* __restrict__ maskp,
                                                        float* __restrict__ out) {
    __shared__ struct {
        union {
            short Ab[2][16640];       // 2 x 32.5 KB A-tile (stride-65 chunks)
            float outb[64 * 257];     // epilogue transpose, pad 257
        } mix;
        int desc[4608];               // 9 kk x 64 m x 8 dwords = 18 KB
    } sm;
    int tid  = threadIdx.x;
    int m0   = blockIdx.x * 64;
    int b    = m0 >> 12;
    int h    = (m0 >> 6) & 63;        // block = full (b,h) row, w 0..63
    int wv   = __builtin_amdgcn_readfirstlane(tid >> 6);   // 0..15
    int lane = tid & 63;
    int q    = lane >> 4, r = lane & 15;
    // sampling write base (shorts): chunk 65*(lane>>1), half (lane&1)
    int wbase = 65 * (lane >> 1) * 8 + (lane & 1) * 4;
    int lane4 = lane * 4;
    int wv4   = wv * 4;

    // ---- one-time descriptor compute: thread t<576 -> desc (kk, m) ----
    if (tid < 576) {
        int kk = tid >> 6;
        int m  = tid & 63;            // = w
        int p  = h * 64 + m;
        int ki = kk / 3, kj = kk - ki * 3;
        float dy = offs[(b * 18 + 2 * kk) * HWN + p];
        float dx = offs[(b * 18 + 2 * kk + 1) * HWN + p];
        float mv = maskp[(b * 9 + kk) * HWN + p];
        float py = (float)(h - 1 + ki) + dy;
        float px = (float)(m - 1 + kj) + dx;
        float y0f = floorf(py), x0f = floorf(px);
        float wy = py - y0f, wx = px - x0f;
        int y0 = (int)y0f, x0 = (int)x0f;
        int4v cb; float4v cw;
        #pragma unroll
        for (int cy = 0; cy < 2; ++cy)
            #pragma unroll
            for (int cx = 0; cx < 2; ++cx) {
                int yy = y0 + cy, xx = x0 + cx;
                bool valid = (yy >= 0 && yy < HN && xx >= 0 && xx < WN);
                int yc = min(max(yy, 0), HN - 1);
                int xc = min(max(xx, 0), WN - 1);
                cb[cy * 2 + cx] = ((b * HN + yc) * WN + xc) * CN;
                float wgt = (cy ? wy : 1.f - wy) * (cx ? wx : 1.f - wx) * mv;
                cw[cy * 2 + cx] = valid ? wgt : 0.f;
            }
        int* dd = &sm.desc[tid * 8];
        *(int4v*)dd       = cb;
        *(float4v*)(dd + 4) = cw;
    }
    __syncthreads();

    frag_cd acc[2][2];
    #pragma unroll
    for (int i = 0; i < 2; ++i)
        #pragma unroll
        for (int j = 0; j < 2; ++j)
            acc[i][j] = (frag_cd){0.f, 0.f, 0.f, 0.f};

    short4v stg[4][4];    // prefetched corner rows (32 VGPR)
    float4v cwc[4];       // corner weights for the prefetched kk

    auto prefetch = [&](int kk1) {
        #pragma unroll
        for (int i = 0; i < 4; ++i) {
            int dbase = (kk1 * 64 + wv4 + i) * 8;     // wave-uniform -> bcast
            int4v cb = *(const int4v*)&sm.desc[dbase];
            cwc[i]   = *(const float4v*)&sm.desc[dbase + 4];
            #pragma unroll
            for (int c = 0; c < 4; ++c)               // coalesced 512B rows
                stg[i][c] = *(const short4v*)&xb16[cb[c] + lane4];
        }
    };

    int wg = wv >> 3;                 // row half 0..1
    int cg = wv & 7;                  // 32-col group 0..7
    int ob = cg >> 1;                 // 64-col block in wtb
    int oh = (cg & 1) * 32;           // 32-col half within it
    auto ld_bf = [&](int kk, int ks, int j) {
        return *(const frag_ab*)
            &wtb[(((size_t)ob * KC + kk * 32 + ks * 4 + q) * 64
                  + oh + j * 16 + r) * 8];
    };

    prefetch(0);

    for (int kk = 0; kk < KKN; ++kk) {
        short* dst = sm.mix.Ab[kk & 1];
        // ---- B pipeline head: ks0/ks1 issued before combine (older than
        // stg(kk+1); in-order vmcnt => bf waits don't drain stg).
        frag_ab bfx[2][2];
        #pragma unroll
        for (int j = 0; j < 2; ++j) {
            bfx[0][j] = ld_bf(kk, 0, j);
            bfx[1][j] = ld_bf(kk, 1, j);
        }
        // ---- combine phase: weighted 4-corner sum -> bf16 A-tile ----
        #pragma unroll
        for (int i = 0; i < 4; ++i) {
            float4v cw = cwc[i];
            short4v res;
            #pragma unroll
            for (int g = 0; g < 2; ++g) {             // channel pairs
                float2v a = (float2v){0.f, 0.f};
                #pragma unroll
                for (int c = 0; c < 4; ++c) {
                    uint2v uv = __builtin_bit_cast(uint2v, stg[i][c]);
                    unsigned uu = uv[g];
                    float2v f;
                    f.x = __builtin_bit_cast(float, uu << 16);
                    f.y = __builtin_bit_cast(float, uu & 0xffff0000u);
                    a += f * cw[c];
                }
                __hip_bfloat162 p2 = __float22bfloat162_rn(make_float2(a.x, a.y));
                res[2 * g]     = *(short*)&p2.x;
                res[2 * g + 1] = *(short*)&p2.y;
            }
            *(short4v*)&dst[wbase + (wv4 + i) * 8] = res;   // ds_write_b64
        }
        // ---- T14: next kk's gathers stay in flight ACROSS the barrier ----
        if (kk < 8) prefetch(kk + 1);
        // ---- non-draining barrier: LDS ordering only ----
        asm volatile("s_waitcnt lgkmcnt(0)" ::: "memory");
        __builtin_amdgcn_s_barrier();
        asm volatile("" ::: "memory");
        // ---- MFMA phase: 8 k16-steps; A from LDS (32 rows), B 2-ahead ----
        #pragma unroll
        for (int ks = 0; ks < 8; ++ks) {
            const int cur = ks & 1;
            frag_ab af[2];
            #pragma unroll
            for (int i = 0; i < 2; ++i)
                af[i] = *(const frag_ab*)
                    &dst[(65 * (ks * 4 + q) + wg * 32 + i * 16 + r) * 8];
            __builtin_amdgcn_s_setprio(1);
            #pragma unroll
            for (int i = 0; i < 2; ++i)
                #pragma unroll
                for (int j = 0; j < 2; ++j)
                    acc[i][j] = __builtin_amdgcn_mfma_f32_16x16x32_bf16(
                        af[i], bfx[cur][j], acc[i][j], 0, 0, 0);
            __builtin_amdgcn_s_setprio(0);
            if (ks < 6) {
                #pragma unroll
                for (int j = 0; j < 2; ++j)
                    bfx[cur][j] = ld_bf(kk, ks + 2, j);
            }
        }
        // no trailing barrier: next kk writes the other buffer; the barrier
        // at kk+1 orders mfma(kk) before any combine(kk+2) buffer reuse.
    }
    __syncthreads();

    // ---- epilogue: acc row=wg*32+i*16+q*4+reg, col=cg*32+j*16+r ----
    #pragma unroll
    for (int i = 0; i < 2; ++i)
        #pragma unroll
        for (int j = 0; j < 2; ++j) {
            int ml = wg * 32 + i * 16 + q * 4;
            int ol = cg * 32 + j * 16 + r;
            sm.mix.outb[(ml + 0) * 257 + ol] = acc[i][j][0];
            sm.mix.outb[(ml + 1) * 257 + ol] = acc[i][j][1];
            sm.mix.outb[(ml + 2) * 257 + ol] = acc[i][j][2];
            sm.mix.outb[(ml + 3) * 257 + ol] = acc[i][j][3];
        }
    __syncthreads();
    {
        int ww = tid & 63;        // w within row
        int og = tid >> 6;        // 0..15
        #pragma unroll
        for (int oo = 0; oo < 16; ++oo) {
            int o = oo * 16 + og;
            out[(((size_t)b * ON + o) * HN + h) * WN + ww] =
                sm.mix.outb[ww * 257 + o];
        }
    }
}

extern "C" void kernel_launch(void* const* d_in, const int* in_sizes, int n_in,
                              void* d_out, int out_size, void* d_ws, size_t ws_size,
                              hipStream_t stream) {
    const float* x      = (const float*)d_in[0];
    const float* offset = (const float*)d_in[1];
    const float* mask   = (const float*)d_in[2];
    const float* weight = (const float*)d_in[3];
    float* out = (float*)d_out;

    // ws: xb16 bf16 8 MiB | wtb (B') bf16 1.125 MiB
    short* xb16 = (short*)d_ws;
    short* wtb  = (short*)((char*)d_ws + 8388608);

    hipLaunchKernelGGL(prep_kernel,  dim3(1312), dim3(256),  0, stream,
                       x, weight, xb16, wtb);
    hipLaunchKernelGGL(fused_kernel, dim3(256),  dim3(1024), 0, stream,
                       xb16, wtb, offset, mask, out);
}

// Round 7
// 115.774 us; speedup vs baseline: 1.0547x; 1.0547x over previous
//
#include <hip/hip_runtime.h>
#include <hip/hip_bf16.h>

// Problem: x(4,256,64,64), offset(4,18,64,64), mask(4,9,64,64),
// weight(256,256,3,3) -> out(4,256,64,64). stride=1, pad=1, K=3.
// R17: producer/consumer wave specialization.
// R16 post-mortem: conflicts halved as predicted but dur 47->52 (B VMEM
// doubled) -> VMEM is the tighter pipe. Per-CU model (R15): A-LDS 22us,
// VMEM 17us, VALU 14us, MFMA 9us, sum ~= measured 47-52 -> phases fully
// serialize; they are 4 DIFFERENT pipes. Fix: 8 C-waves (64x32 GEMM tile:
// A-amp 8, B dup 1, acc 4x2) + 8 P-waves (sample 8 rows each, 2-row
// ping-pong gather pipeline). Per kk: C consumes buf[kk&1] while P
// produces buf[(kk+1)&1]; one lgkmcnt(0)+s_barrier tick per kk (vmcnt NOT
// drained -> gathers/B-loads fly across barriers). VALU(P) now overlaps
// MFMA+DS+VMEM(C). setprio(1) on C's MFMA (role-diverse waves = T5's
// paying regime).
#define CN 256
#define HN 64
#define WN 64
#define ON 256
#define KKN 9
#define HWN 4096
#define KDIM 2304   // 9*256
#define KC 288      // KDIM/8 chunks

using frag_ab = __attribute__((ext_vector_type(8))) short;  // 8 bf16
using frag_cd = __attribute__((ext_vector_type(4))) float;  // 4 fp32
using short4v = __attribute__((ext_vector_type(4))) short;  // 4 bf16 (8B)
using int4v   = __attribute__((ext_vector_type(4))) int;
using float4v = __attribute__((ext_vector_type(4))) float;
using float2v = __attribute__((ext_vector_type(2))) float;
using uint2v  = __attribute__((ext_vector_type(2))) unsigned;

static __device__ inline short f2bf(float f) {
    union { float f; unsigned u; } v; v.f = f;
    unsigned r = v.u + 0x7fffu + ((v.u >> 16) & 1u);
    return (short)(r >> 16);
}

// ---------- kernel 1: prep = transpose x -> BHWC bf16 | repack weight ----
__global__ __launch_bounds__(256) void prep_kernel(const float* __restrict__ x,
                                                   const float* __restrict__ wsrc,
                                                   short* __restrict__ xb16,
                                                   short* __restrict__ wtb) {
    int bidx = blockIdx.x;
    int tid  = threadIdx.x;
    if (bidx < 1024) {
        __shared__ float tile[64][65];
        int b   = bidx >> 8;
        int rem = bidx & 255;
        int c0  = (rem >> 6) * 64;
        int p0  = (rem & 63) * 64;
        int tp = tid & 63, tc = tid >> 6;
        for (int i = 0; i < 16; ++i) {
            int c = tc + i * 4;
            tile[c][tp] = x[(b * CN + c0 + c) * HWN + p0 + tp];
        }
        __syncthreads();
        int tcc = tid & 63, tpp = tid >> 6;
        for (int i = 0; i < 16; ++i) {
            int p = tpp + i * 4;
            xb16[(b * HWN + p0 + p) * CN + c0 + tcc] = f2bf(tile[tcc][p]);
        }
    } else {
        int chunk = (bidx - 1024) * 256 + tid;   // < 4*288*64 = 73728
        int ob  = chunk / (KC * 64);
        int rem = chunk - ob * (KC * 64);
        int kc  = rem >> 6;
        int row = rem & 63;
        int o   = ob * 64 + row;
        int kk  = kc >> 5;
        int oct = kc & 31;
        frag_ab v;
        #pragma unroll
        for (int e = 0; e < 8; ++e)
            v[e] = f2bf(wsrc[(o * CN + oct * 8 + e) * 9 + kk]);
        *(frag_ab*)&wtb[(size_t)chunk * 8] = v;
    }
}

// ---------- kernel 2: fused sample + GEMM, producer/consumer ----------
// block: 64 m-rows (one (b,h) row) x 256 o-cols, 16 waves, grid 256.
// C-waves wv 0..7: GEMM tile rows 0..63 x cols wv*32..+32 (acc 4x2).
// P-waves wv 8..15: sample rows (wv-8)*8..+8 into A buf[(kk+1)&1].
// One lgkmcnt(0)+s_barrier per kk; vmcnt never drained in the loop.
__global__ __launch_bounds__(1024, 4) void fused_kernel(const short* __restrict__ xb16,
                                                        const short* __restrict__ wtb,
                                                        const float* __restrict__ offs,
                                                        const float* __restrict__ maskp,
                                                        float* __restrict__ out) {
    __shared__ struct {
        union {
            short Ab[2][16640];       // 2 x 32.5 KB A-tile (stride-65 chunks)
            float outb[64 * 257];     // epilogue transpose, pad 257
        } mix;
        int desc[4608];               // 9 kk x 64 m x 8 dwords = 18 KB
    } sm;
    int tid  = threadIdx.x;
    int m0   = blockIdx.x * 64;
    int b    = m0 >> 12;
    int h    = (m0 >> 6) & 63;        // block = full (b,h) row, w 0..63
    int wv   = __builtin_amdgcn_readfirstlane(tid >> 6);   // 0..15
    int lane = tid & 63;
    int q    = lane >> 4, r = lane & 15;
    // sampling write base (shorts): chunk 65*(lane>>1), half (lane&1)
    int wbase = 65 * (lane >> 1) * 8 + (lane & 1) * 4;
    int lane4 = lane * 4;

    // ---- one-time descriptor compute: thread t<576 -> desc (kk, m) ----
    if (tid < 576) {
        int kk = tid >> 6;
        int m  = tid & 63;            // = w
        int p  = h * 64 + m;
        int ki = kk / 3, kj = kk - ki * 3;
        float dy = offs[(b * 18 + 2 * kk) * HWN + p];
        float dx = offs[(b * 18 + 2 * kk + 1) * HWN + p];
        float mv = maskp[(b * 9 + kk) * HWN + p];
        float py = (float)(h - 1 + ki) + dy;
        float px = (float)(m - 1 + kj) + dx;
        float y0f = floorf(py), x0f = floorf(px);
        float wy = py - y0f, wx = px - x0f;
        int y0 = (int)y0f, x0 = (int)x0f;
        int4v cb; float4v cw;
        #pragma unroll
        for (int cy = 0; cy < 2; ++cy)
            #pragma unroll
            for (int cx = 0; cx < 2; ++cx) {
                int yy = y0 + cy, xx = x0 + cx;
                bool valid = (yy >= 0 && yy < HN && xx >= 0 && xx < WN);
                int yc = min(max(yy, 0), HN - 1);
                int xc = min(max(xx, 0), WN - 1);
                cb[cy * 2 + cx] = ((b * HN + yc) * WN + xc) * CN;
                float wgt = (cy ? wy : 1.f - wy) * (cx ? wx : 1.f - wx) * mv;
                cw[cy * 2 + cx] = valid ? wgt : 0.f;
            }
        int* dd = &sm.desc[tid * 8];
        *(int4v*)dd       = cb;
        *(float4v*)(dd + 4) = cw;
    }
    __syncthreads();

    bool isP = (wv >= 8);
    int  pw8 = (wv - 8) * 8;          // P: first sampled row

    // ---- P-wave helpers: 2-row gather / combine ----
    auto g2 = [&](short4v (&stg)[2][4], int t, int roff) {
        #pragma unroll
        for (int i = 0; i < 2; ++i) {
            int dbase = (t * 64 + pw8 + roff + i) * 8;   // wave-uniform bcast
            int4v cb = *(const int4v*)&sm.desc[dbase];
            #pragma unroll
            for (int c = 0; c < 4; ++c)                  // coalesced 512B rows
                stg[i][c] = *(const short4v*)&xb16[cb[c] + lane4];
        }
    };
    auto c2 = [&](short4v (&stg)[2][4], short* dstp, int t, int roff) {
        #pragma unroll
        for (int i = 0; i < 2; ++i) {
            int mloc = pw8 + roff + i;
            float4v cw = *(const float4v*)&sm.desc[(t * 64 + mloc) * 8 + 4];
            short4v res;
            #pragma unroll
            for (int g = 0; g < 2; ++g) {                // channel pairs
                float2v a = (float2v){0.f, 0.f};
                #pragma unroll
                for (int c = 0; c < 4; ++c) {
                    uint2v uv = __builtin_bit_cast(uint2v, stg[i][c]);
                    unsigned uu = uv[g];
                    float2v f;
                    f.x = __builtin_bit_cast(float, uu << 16);
                    f.y = __builtin_bit_cast(float, uu & 0xffff0000u);
                    a += f * cw[c];
                }
                __hip_bfloat162 p2 = __float22bfloat162_rn(make_float2(a.x, a.y));
                res[2 * g]     = *(short*)&p2.x;
                res[2 * g + 1] = *(short*)&p2.y;
            }
            *(short4v*)&dstp[wbase + mloc * 8] = res;    // ds_write_b64
        }
    };
    auto produce = [&](int t) {
        short* dstp = sm.mix.Ab[t & 1];
        short4v sA[2][4], sB[2][4];
        g2(sA, t, 0);                 // rows 0-1 in flight
        g2(sB, t, 2);                 // rows 2-3 in flight
        c2(sA, dstp, t, 0);
        g2(sA, t, 4);
        c2(sB, dstp, t, 2);
        g2(sB, t, 6);
        c2(sA, dstp, t, 4);
        c2(sB, dstp, t, 6);
    };

    // ---- C-wave state ----
    frag_cd acc[4][2];
    #pragma unroll
    for (int i = 0; i < 4; ++i)
        #pragma unroll
        for (int j = 0; j < 2; ++j)
            acc[i][j] = (frag_cd){0.f, 0.f, 0.f, 0.f};
    int ob = wv >> 1;                 // 64-col block in wtb (C waves: wv 0..7)
    int oh = (wv & 1) * 32;           // 32-col half within it
    auto ld_bf = [&](int kk, int ks, int j) {
        return *(const frag_ab*)
            &wtb[(((size_t)ob * KC + kk * 32 + ks * 4 + q) * 64
                  + oh + j * 16 + r) * 8];
    };
    auto consume = [&](int kk) {
        const short* dstc = sm.mix.Ab[kk & 1];
        frag_ab bfx[2][2];
        #pragma unroll
        for (int j = 0; j < 2; ++j) {
            bfx[0][j] = ld_bf(kk, 0, j);
            bfx[1][j] = ld_bf(kk, 1, j);
        }
        #pragma unroll
        for (int ks = 0; ks < 8; ++ks) {
            const int cur = ks & 1;
            frag_ab af[4];
            #pragma unroll
            for (int i = 0; i < 4; ++i)
                af[i] = *(const frag_ab*)
                    &dstc[(65 * (ks * 4 + q) + i * 16 + r) * 8];
            __builtin_amdgcn_s_setprio(1);
            #pragma unroll
            for (int i = 0; i < 4; ++i)
                #pragma unroll
                for (int j = 0; j < 2; ++j)
                    acc[i][j] = __builtin_amdgcn_mfma_f32_16x16x32_bf16(
                        af[i], bfx[cur][j], acc[i][j], 0, 0, 0);
            __builtin_amdgcn_s_setprio(0);
            if (ks < 6) {
                #pragma unroll
                for (int j = 0; j < 2; ++j)
                    bfx[cur][j] = ld_bf(kk, ks + 2, j);
            }
        }
    };

    // ---- prologue: P builds tile 0; C idles ----
    if (isP) produce(0);
    asm volatile("s_waitcnt lgkmcnt(0)" ::: "memory");
    __builtin_amdgcn_s_barrier();
    asm volatile("" ::: "memory");

    // ---- main loop: C consumes buf[kk&1] while P produces buf[(kk+1)&1].
    for (int kk = 0; kk < KKN; ++kk) {
        if (isP) {
            if (kk < 8) produce(kk + 1);
        } else {
            consume(kk);
        }
        asm volatile("s_waitcnt lgkmcnt(0)" ::: "memory");
        __builtin_amdgcn_s_barrier();
        asm volatile("" ::: "memory");
    }

    // ---- epilogue: C writes acc (row=i*16+q*4+reg, col=wv*32+j*16+r) ----
    if (!isP) {
        #pragma unroll
        for (int i = 0; i < 4; ++i)
            #pragma unroll
            for (int j = 0; j < 2; ++j) {
                int ml = i * 16 + q * 4;
                int ol = wv * 32 + j * 16 + r;
                sm.mix.outb[(ml + 0) * 257 + ol] = acc[i][j][0];
                sm.mix.outb[(ml + 1) * 257 + ol] = acc[i][j][1];
                sm.mix.outb[(ml + 2) * 257 + ol] = acc[i][j][2];
                sm.mix.outb[(ml + 3) * 257 + ol] = acc[i][j][3];
            }
    }
    __syncthreads();
    {
        int ww = tid & 63;        // w within row
        int og = tid >> 6;        // 0..15
        #pragma unroll
        for (int oo = 0; oo < 16; ++oo) {
            int o = oo * 16 + og;
            out[(((size_t)b * ON + o) * HN + h) * WN + ww] =
                sm.mix.outb[ww * 257 + o];
        }
    }
}

extern "C" void kernel_launch(void* const* d_in, const int* in_sizes, int n_in,
                              void* d_out, int out_size, void* d_ws, size_t ws_size,
                              hipStream_t stream) {
    const float* x      = (const float*)d_in[0];
    const float* offset = (const float*)d_in[1];
    const float* mask   = (const float*)d_in[2];
    const float* weight = (const float*)d_in[3];
    float* out = (float*)d_out;

    // ws: xb16 bf16 8 MiB | wtb (B') bf16 1.125 MiB
    short* xb16 = (short*)d_ws;
    short* wtb  = (short*)((char*)d_ws + 8388608);

    hipLaunchKernelGGL(prep_kernel,  dim3(1312), dim3(256),  0, stream,
                       x, weight, xb16, wtb);
    hipLaunchKernelGGL(fused_kernel, dim3(256),  dim3(1024), 0, stream,
                       xb16, wtb, offset, mask, out);
}